// Round 1
// baseline (255.894 us; speedup 1.0000x reference)
//
#include <hip/hip_runtime.h>
#include <hip/hip_cooperative_groups.h>

namespace cg = cooperative_groups;

// B=2, N=256, E=768, H=12, D=64. Inputs fp32, output fp32.
//
// Exact-math shortcut (validated in prior session):
//   attn scores (1+g/10)^-64.5 <= ~4e-9 uniformly => softmax uniform to 4e-9
//   => attn_out[b,h,i,:] = mean_j V[b,h,j,:] (independent of i)
//   => out = LN(hs + reshape_raw(tiled col-means of V) @ Wo + bo)
//
// R7: single cooperative launch. rocprof showed the 4-kernel pipeline's time
// is dominated by launch+dependency gaps (~2-4 us each), not by work (~10 MB
// unique traffic total, mostly L2-resident). One kernel, grid.sync() between
// phases, removes 3 launch/gap cycles. Math is bit-identical to the 4-kernel
// version; a runtime fallback to the 4-kernel path is kept.
//
// ws layout (bytes):
//   p     f32[2][32][768]     @ 0        (196608)  row-group partial colsums
//   Mpart f32[2][16][768]     @ 196608   ( 98304)  i-chunk partial M
//   T     f32[2][12][12][768] @ 294912   (884736)
// total 1,179,648 B.

// ---------------- fused cooperative kernel ----------------
__global__ __launch_bounds__(256, 2) void fused_kernel(
    const float* __restrict__ hs, const float* __restrict__ Wv,
    const float* __restrict__ bv, const float* __restrict__ Wo,
    const float* __restrict__ bo, const float* __restrict__ ln_g,
    const float* __restrict__ ln_b, float* __restrict__ p,
    float* __restrict__ Mpart, float* __restrict__ T,
    float* __restrict__ out)
{
    cg::grid_group grid = cg::this_grid();
    const int bid = blockIdx.x;
    const int t = threadIdx.x;
    __shared__ float sm[256];

    // ---- Phase 1: partial colsums (blocks 0..63): (b, rg) ----
    if (bid < 64) {
        const int b = bid >> 5, rg = bid & 31;
        const float* base = hs + b * 196608 + rg * (8 * 768);
        float s0 = 0.f, s1 = 0.f, s2 = 0.f;
        #pragma unroll
        for (int r = 0; r < 8; ++r) {
            const float* row = base + r * 768;
            s0 += row[t];
            s1 += row[t + 256];
            s2 += row[t + 512];
        }
        float* pp = p + (b * 32 + rg) * 768;
        pp[t] = s0; pp[t + 256] = s1; pp[t + 512] = s2;
    }
    grid.sync();

    // ---- Phase 2: partial M (blocks 0..95): (b, eg<3, ic<16) ----
    if (bid < 96) {
        const int b = bid / 48, rem = bid % 48, eg = rem / 16, ic = rem % 16;
        if (t < 48) {
            const int i = ic * 48 + t;
            float s = 0.f;
            #pragma unroll 8
            for (int rg = 0; rg < 32; ++rg) s += p[(b * 32 + rg) * 768 + i];
            sm[t] = s;
        }
        __syncthreads();
        const int e = eg * 256 + t;
        float acc = 0.f;
        #pragma unroll 4
        for (int ii = 0; ii < 48; ++ii)
            acc += sm[ii] * Wv[(ic * 48 + ii) * 768 + e];
        Mpart[(b * 16 + ic) * 768 + e] = acc;
    }
    grid.sync();

    // ---- Phase 3: T[b][hh][c][e] (blocks 0..287): (b, hh, c) ----
    if (bid < 288) {
        const int b = bid / 144, rem = bid % 144, hh = rem / 12, c = rem % 12;
        if (t < 64) {
            const int col = hh * 64 + t;
            float m = 0.f;
            #pragma unroll
            for (int ic = 0; ic < 16; ++ic) m += Mpart[(b * 16 + ic) * 768 + col];
            sm[t] = m * (1.0f / 256.0f) + bv[col];
        }
        __syncthreads();
        #pragma unroll
        for (int r = 0; r < 3; ++r) {
            const int e = t + r * 256;
            const float* wp = Wo + (c * 64) * 768 + e;
            float acc = 0.f;
            #pragma unroll
            for (int d = 0; d < 64; ++d) acc += sm[d] * wp[d * 768];
            T[((b * 12 + hh) * 12 + c) * 768 + e] = acc;
        }
    }
    grid.sync();

    // ---- Phase 4: out (all 512 blocks): (b, n) ----
    {
        const int b = bid >> 8, n = bid & 255;
        const int wave = t >> 6, lane = t & 63;

        float x[3];
        float xs = 0.f;
        #pragma unroll
        for (int r = 0; r < 3; ++r) {
            const int e = t + r * 256;
            float h = bo[e];
            #pragma unroll
            for (int c = 0; c < 12; ++c) {
                const int hc = (12 * n + c) >> 8;
                h += T[((b * 12 + hc) * 12 + c) * 768 + e];
            }
            x[r] = h + hs[(b * 256 + n) * 768 + e];
            xs += x[r];
        }

        // mean: wave shuffle reduce + 4-partial LDS combine
        float wr = xs;
        #pragma unroll
        for (int off = 32; off > 0; off >>= 1) wr += __shfl_down(wr, off, 64);
        if (lane == 0) sm[wave] = wr;
        __syncthreads();
        const float mu = (sm[0] + sm[1] + sm[2] + sm[3]) * (1.0f / 768.0f);
        __syncthreads();

        float vs = 0.f;
        #pragma unroll
        for (int r = 0; r < 3; ++r) { const float c = x[r] - mu; vs += c * c; }
        wr = vs;
        #pragma unroll
        for (int off = 32; off > 0; off >>= 1) wr += __shfl_down(wr, off, 64);
        if (lane == 0) sm[wave] = wr;
        __syncthreads();
        const float rstd = rsqrtf((sm[0] + sm[1] + sm[2] + sm[3]) * (1.0f / 768.0f)
                                  + 1e-12f);

        #pragma unroll
        for (int r = 0; r < 3; ++r) {
            const int e = t + r * 256;
            out[(b * 256 + n) * 768 + e] = (x[r] - mu) * rstd * ln_g[e] + ln_b[e];
        }
    }
}

// ---------------- fallback path (proven 4-kernel pipeline) ----------------
__global__ __launch_bounds__(256) void colsum_kernel(
    const float* __restrict__ hs, float* __restrict__ p)
{
    int b = blockIdx.x, rg = blockIdx.y;
    int t = threadIdx.x;
    const float* base = hs + b * 196608 + rg * 8 * 768;
    float s0 = 0.f, s1 = 0.f, s2 = 0.f;
    #pragma unroll
    for (int r = 0; r < 8; ++r) {
        const float* row = base + r * 768;
        s0 += row[t];
        s1 += row[t + 256];
        s2 += row[t + 512];
    }
    float* pp = p + (b * 32 + rg) * 768;
    pp[t] = s0; pp[t + 256] = s1; pp[t + 512] = s2;
}

__global__ __launch_bounds__(256) void meanv_kernel(
    const float* __restrict__ p, const float* __restrict__ Wv,
    float* __restrict__ Mpart)
{
    int b = blockIdx.x, eg = blockIdx.y, ic = blockIdx.z;
    int t = threadIdx.x;
    __shared__ float hsumL[48];
    if (t < 48) {
        int i = ic * 48 + t;
        float s = 0.f;
        #pragma unroll 8
        for (int rg = 0; rg < 32; ++rg) s += p[(b * 32 + rg) * 768 + i];
        hsumL[t] = s;
    }
    __syncthreads();
    int e = eg * 256 + t;
    float acc = 0.f;
    #pragma unroll 4
    for (int ii = 0; ii < 48; ++ii)
        acc += hsumL[ii] * Wv[(ic * 48 + ii) * 768 + e];
    Mpart[(b * 16 + ic) * 768 + e] = acc;
}

__global__ __launch_bounds__(768) void tmat_kernel(
    const float* __restrict__ Mpart, const float* __restrict__ bv,
    const float* __restrict__ Wo, float* __restrict__ T)
{
    int b = blockIdx.x, hh = blockIdx.y, c = blockIdx.z;
    int e = threadIdx.x;
    __shared__ float mL[64];
    if (e < 64) {
        int col = hh * 64 + e;
        float m = 0.f;
        #pragma unroll
        for (int ic = 0; ic < 16; ++ic) m += Mpart[(b * 16 + ic) * 768 + col];
        mL[e] = m * (1.0f / 256.0f) + bv[col];
    }
    __syncthreads();
    const float* wp = Wo + (c * 64) * 768 + e;
    float acc = 0.f;
    #pragma unroll
    for (int d = 0; d < 64; ++d) acc += mL[d] * wp[d * 768];
    T[((b * 12 + hh) * 12 + c) * 768 + e] = acc;
}

__global__ __launch_bounds__(256) void out_kernel(
    const float* __restrict__ T, const float* __restrict__ hs,
    const float* __restrict__ bo, const float* __restrict__ ln_g,
    const float* __restrict__ ln_b, float* __restrict__ out)
{
    int b = blockIdx.x, n = blockIdx.y;
    int t = threadIdx.x;
    __shared__ float red[256];
    float x[3];
    float xs = 0.f;
    #pragma unroll
    for (int r = 0; r < 3; ++r) {
        int e = t + r * 256;
        float h = bo[e];
        #pragma unroll
        for (int c = 0; c < 12; ++c) {
            int hc = (12 * n + c) >> 8;
            h += T[((b * 12 + hc) * 12 + c) * 768 + e];
        }
        x[r] = h + hs[(b * 256 + n) * 768 + e];
        xs += x[r];
    }
    red[t] = xs;
    __syncthreads();
    for (int s = 128; s > 0; s >>= 1) {
        if (t < s) red[t] += red[t + s];
        __syncthreads();
    }
    float mu = red[0] * (1.0f / 768.0f);
    __syncthreads();
    float vs = 0.f;
    #pragma unroll
    for (int r = 0; r < 3; ++r) { float c = x[r] - mu; vs += c * c; }
    red[t] = vs;
    __syncthreads();
    for (int s = 128; s > 0; s >>= 1) {
        if (t < s) red[t] += red[t + s];
        __syncthreads();
    }
    float rstd = rsqrtf(red[0] * (1.0f / 768.0f) + 1e-12f);
    #pragma unroll
    for (int r = 0; r < 3; ++r) {
        int e = t + r * 256;
        float y = (x[r] - mu) * rstd * ln_g[e] + ln_b[e];
        out[(b * 256 + n) * 768 + e] = y;
    }
}

extern "C" void kernel_launch(void* const* d_in, const int* in_sizes, int n_in,
                              void* d_out, int out_size, void* d_ws, size_t ws_size,
                              hipStream_t stream) {
    const float* hs   = (const float*)d_in[0];
    // d_in[1..5] (mask, Wq, bq, Wk, bk): numerically dead (see header)
    const float* Wv   = (const float*)d_in[6];
    const float* bv   = (const float*)d_in[7];
    const float* Wo   = (const float*)d_in[8];
    const float* bo   = (const float*)d_in[9];
    const float* ln_g = (const float*)d_in[10];
    const float* ln_b = (const float*)d_in[11];

    char* ws = (char*)d_ws;
    float* p     = (float*)(ws + 0);
    float* Mpart = (float*)(ws + 196608);
    float* T     = (float*)(ws + 294912);
    float* outp  = (float*)d_out;

    void* args[] = {
        (void*)&hs, (void*)&Wv, (void*)&bv, (void*)&Wo, (void*)&bo,
        (void*)&ln_g, (void*)&ln_b, (void*)&p, (void*)&Mpart, (void*)&T,
        (void*)&outp
    };
    hipError_t err = hipLaunchCooperativeKernel(
        (const void*)fused_kernel, dim3(512), dim3(256), args, 0, stream);

    if (err != hipSuccess) {
        // Fallback: proven 4-kernel pipeline (bit-identical math).
        colsum_kernel<<<dim3(2, 32),     256, 0, stream>>>(hs, p);
        meanv_kernel <<<dim3(2, 3, 16),  256, 0, stream>>>(p, Wv, Mpart);
        tmat_kernel  <<<dim3(2, 12, 12), 768, 0, stream>>>(Mpart, bv, Wo, T);
        out_kernel   <<<dim3(2, 256),    256, 0, stream>>>(T, hs, bo, ln_g, ln_b,
                                                           outp);
    }
}

// Round 2
// 105.663 us; speedup vs baseline: 2.4218x; 2.4218x over previous
//
#include <hip/hip_runtime.h>

// B=2, N=256, E=768, H=12, D=64. Inputs fp32, output fp32.
//
// Exact-math shortcut (validated in prior session):
//   attn scores (1+g/10)^-64.5 <= ~4e-9 uniformly => softmax uniform to 4e-9
//   => attn_out[b,h,i,:] = mean_j V[b,h,j,:] (independent of i)
//   => out = LN(hs + reshape_raw(tiled col-means of V) @ Wo + bo)
//
// Raw reshape [B,H,N,D]->[B,N,E]: row (b,n) chunk c comes from head hc=(12n+c)>>8:
//   h[b,n,e] = sum_c T[b][hc][c][e],
//   T[b][hh][c][e] = sum_d M[b][hh*64+d] * Wo[c*64+d][e],
//   M[b][:] = (sum_n hs[b,n,:]) @ Wv / 256 + bv.
//
// R8: 4 -> 3 kernels. R7's cooperative single-kernel regressed hard
// (cg::grid.sync() ~50us each on gfx950 at this size; kernel 159us at
// VALUBusy 0.8%). rocprof shows our controllable ~17us is mostly
// launch+dependency gaps (~3us/link), so remove one link by fusing
// colsum+meanv: each meanv block only needs a 48-column colsum (49KB of hs),
// computed in-block in the EXACT same fp32 summation order as before
// (8-row groups ascending, then rg ascending) => bit-identical output.
// tmat/out kernels are the proven R6 versions, unchanged.
//
// ws layout (bytes) — offsets kept from R6 (p slot now unused):
//   Mpart f32[2][16][768]     @ 196608   ( 98304)  i-chunk partial M
//   T     f32[2][12][12][768] @ 294912   (884736)

// ---- K1: fused colsum+meanv. grid (2,16), block 256. Block: (b, i-chunk). ----
__global__ __launch_bounds__(256) void msum_kernel(
    const float* __restrict__ hs, const float* __restrict__ Wv,
    float* __restrict__ Mpart)
{
    const int b = blockIdx.x, ic = blockIdx.y;
    const int t = threadIdx.x;
    __shared__ float pL[32][48];   // 8-row-group partial colsums for our 48 cols
    __shared__ float hsumL[48];

    // Stage A: 1536 (rg, j) partials, 6 per thread. Same inner order as old
    // colsum_kernel: 8 consecutive rows summed sequentially.
    #pragma unroll
    for (int q = 0; q < 6; ++q) {
        const int idx = q * 256 + t;        // 0..1535
        const int rg = idx / 48, j = idx % 48;
        const float* pb = hs + b * 196608 + (rg * 8) * 768 + ic * 48 + j;
        float s = 0.f;
        #pragma unroll
        for (int r = 0; r < 8; ++r) s += pb[r * 768];
        pL[rg][j] = s;
    }
    __syncthreads();

    // Stage B: reduce rg ascending (same order as old meanv's p-reduction).
    if (t < 48) {
        float s = 0.f;
        #pragma unroll 8
        for (int rg = 0; rg < 32; ++rg) s += pL[rg][t];
        hsumL[t] = s;
    }
    __syncthreads();

    // Stage C: partial M over this i-chunk for all 768 e (old meanv stage,
    // ii ascending => bit-identical).
    #pragma unroll
    for (int r = 0; r < 3; ++r) {
        const int e = r * 256 + t;
        float acc = 0.f;
        #pragma unroll 4
        for (int ii = 0; ii < 48; ++ii)
            acc += hsumL[ii] * Wv[(ic * 48 + ii) * 768 + e];
        Mpart[(b * 16 + ic) * 768 + e] = acc;
    }
}

// ---- K2: T[b][hh][c][e] = sum_d M[b][hh*64+d] * Wo[c*64+d][e]. grid (2,12,12). ----
__global__ __launch_bounds__(768) void tmat_kernel(
    const float* __restrict__ Mpart, const float* __restrict__ bv,
    const float* __restrict__ Wo, float* __restrict__ T)
{
    int b = blockIdx.x, hh = blockIdx.y, c = blockIdx.z;
    int e = threadIdx.x;
    __shared__ float mL[64];

    if (e < 64) {
        int col = hh * 64 + e;
        float m = 0.f;
        #pragma unroll
        for (int ic = 0; ic < 16; ++ic) m += Mpart[(b * 16 + ic) * 768 + col];
        mL[e] = m * (1.0f / 256.0f) + bv[col];
    }
    __syncthreads();

    const float* wp = Wo + (c * 64) * 768 + e;
    float acc = 0.f;
    #pragma unroll
    for (int d = 0; d < 64; ++d) acc += mL[d] * wp[d * 768];
    T[((b * 12 + hh) * 12 + c) * 768 + e] = acc;
}

// ---- K3: per (b,n): h[e] = bo[e] + sum_c T[b][hc(n,c)][c][e]; +hs; LayerNorm. ----
__global__ __launch_bounds__(256) void out_kernel(
    const float* __restrict__ T, const float* __restrict__ hs,
    const float* __restrict__ bo, const float* __restrict__ ln_g,
    const float* __restrict__ ln_b, float* __restrict__ out)
{
    int b = blockIdx.x, n = blockIdx.y;
    int t = threadIdx.x;
    __shared__ float red[256];

    float x[3];
    float xs = 0.f;
    #pragma unroll
    for (int r = 0; r < 3; ++r) {
        int e = t + r * 256;
        float h = bo[e];
        #pragma unroll
        for (int c = 0; c < 12; ++c) {
            int hc = (12 * n + c) >> 8;
            h += T[((b * 12 + hc) * 12 + c) * 768 + e];
        }
        x[r] = h + hs[(b * 256 + n) * 768 + e];
        xs += x[r];
    }

    red[t] = xs;
    __syncthreads();
    for (int s = 128; s > 0; s >>= 1) {
        if (t < s) red[t] += red[t + s];
        __syncthreads();
    }
    float mu = red[0] * (1.0f / 768.0f);
    __syncthreads();

    float vs = 0.f;
    #pragma unroll
    for (int r = 0; r < 3; ++r) { float c = x[r] - mu; vs += c * c; }
    red[t] = vs;
    __syncthreads();
    for (int s = 128; s > 0; s >>= 1) {
        if (t < s) red[t] += red[t + s];
        __syncthreads();
    }
    float rstd = rsqrtf(red[0] * (1.0f / 768.0f) + 1e-12f);

    #pragma unroll
    for (int r = 0; r < 3; ++r) {
        int e = t + r * 256;
        float y = (x[r] - mu) * rstd * ln_g[e] + ln_b[e];
        out[(b * 256 + n) * 768 + e] = y;
    }
}

extern "C" void kernel_launch(void* const* d_in, const int* in_sizes, int n_in,
                              void* d_out, int out_size, void* d_ws, size_t ws_size,
                              hipStream_t stream) {
    const float* hs   = (const float*)d_in[0];
    // d_in[1..5] (mask, Wq, bq, Wk, bk): numerically dead (see header)
    const float* Wv   = (const float*)d_in[6];
    const float* bv   = (const float*)d_in[7];
    const float* Wo   = (const float*)d_in[8];
    const float* bo   = (const float*)d_in[9];
    const float* ln_g = (const float*)d_in[10];
    const float* ln_b = (const float*)d_in[11];

    char* ws = (char*)d_ws;
    float* Mpart = (float*)(ws + 196608);
    float* T     = (float*)(ws + 294912);

    msum_kernel<<<dim3(2, 16),     256, 0, stream>>>(hs, Wv, Mpart);
    tmat_kernel<<<dim3(2, 12, 12), 768, 0, stream>>>(Mpart, bv, Wo, T);
    out_kernel <<<dim3(2, 256),    256, 0, stream>>>(T, hs, bo, ln_g, ln_b,
                                                     (float*)d_out);
}

// Round 3
// 95.254 us; speedup vs baseline: 2.6864x; 1.1093x over previous
//
#include <hip/hip_runtime.h>

// B=2, N=256, E=768, H=12, D=64. Inputs fp32, output fp32.
//
// Exact-math shortcut (validated in prior session):
//   attn scores (1+g/10)^-64.5 <= ~4e-9 uniformly => softmax uniform to 4e-9
//   => attn_out[b,h,i,:] = mean_j V[b,h,j,:] (independent of i)
//   => out = LN(hs + reshape_raw(tiled col-means of V) @ Wo + bo)
//
// Raw reshape [B,H,N,D]->[B,N,E]: row (b,n) chunk c comes from head hc=(12n+c)>>8:
//   h[b,n,e] = sum_c T[b][hc][c][e],
//   T[b][hh][c][e] = sum_d M[b][hh*64+d] * Wo[c*64+d][e],
//   M[b][:] = (sum_n hs[b,n,:]) @ Wv / 256 + bv.
//
// R9: keep the 3-kernel pipeline (colsum+meanv fused) but fix the fused
// kernel's execution quality. R8's msum ran on 32 blocks with scalar
// stride-3072B loads and div/mod-48 indexing -> slower than the two kernels
// it replaced (105.7 vs 100.7). Now: i-chunks of 64 (12 chunks), grid
// (2,3,12)=72 blocks (colsum replicated per e-range: +3x L2-resident hs
// reads, 2.25x more CUs), float4 stage A, conflict-free LDS reduce, lane-
// coalesced Wv reads. tmat/out are the proven R6 kernels (tmat reduces 12
// partials now).
//
// ws layout (bytes):
//   Mpart f32[2][12][768]     @ 196608   ( 73728)  i-chunk partial M
//   T     f32[2][12][12][768] @ 294912   (884736)

// ---- K1: fused colsum+meanv. grid (2,3,12), block 256: (b, e-range, i-chunk). ----
__global__ __launch_bounds__(256) void msum_kernel(
    const float* __restrict__ hs, const float* __restrict__ Wv,
    float* __restrict__ Mpart)
{
    const int b = blockIdx.x, eg = blockIdx.y, ic = blockIdx.z;
    const int t = threadIdx.x;
    __shared__ float pL[16][64];   // 16-row-group partial colsums, our 64 cols
    __shared__ float hsumL[64];

    // Stage A: thread (rgrp, j4) sums 16 consecutive rows of one float4 column
    // group. Per 16-lane group: 256B contiguous loads.
    {
        const int j4 = t & 15;          // float4 chunk within 64 cols
        const int rgrp = t >> 4;        // 16-row group
        const float* pb = hs + b * 196608 + (rgrp * 16) * 768 + ic * 64 + j4 * 4;
        float4 s = make_float4(0.f, 0.f, 0.f, 0.f);
        #pragma unroll
        for (int r = 0; r < 16; ++r) {
            const float4 v = *(const float4*)(pb + r * 768);
            s.x += v.x; s.y += v.y; s.z += v.z; s.w += v.w;
        }
        *(float4*)&pL[rgrp][j4 * 4] = s;
    }
    __syncthreads();

    // Stage B: reduce 16 row-group partials per column (2-way LDS alias, free).
    if (t < 64) {
        float s = 0.f;
        #pragma unroll
        for (int g = 0; g < 16; ++g) s += pL[g][t];
        hsumL[t] = s;
    }
    __syncthreads();

    // Stage C: partial M for this i-chunk over our 256-e range (coalesced).
    const int e = eg * 256 + t;
    float acc = 0.f;
    #pragma unroll 8
    for (int ii = 0; ii < 64; ++ii)
        acc += hsumL[ii] * Wv[(ic * 64 + ii) * 768 + e];
    Mpart[(b * 12 + ic) * 768 + e] = acc;
}

// ---- K2: T[b][hh][c][e] = sum_d M[b][hh*64+d] * Wo[c*64+d][e]. grid (2,12,12). ----
__global__ __launch_bounds__(768) void tmat_kernel(
    const float* __restrict__ Mpart, const float* __restrict__ bv,
    const float* __restrict__ Wo, float* __restrict__ T)
{
    int b = blockIdx.x, hh = blockIdx.y, c = blockIdx.z;
    int e = threadIdx.x;
    __shared__ float mL[64];

    if (e < 64) {
        int col = hh * 64 + e;
        float m = 0.f;
        #pragma unroll
        for (int ic = 0; ic < 12; ++ic) m += Mpart[(b * 12 + ic) * 768 + col];
        mL[e] = m * (1.0f / 256.0f) + bv[col];
    }
    __syncthreads();

    const float* wp = Wo + (c * 64) * 768 + e;
    float acc = 0.f;
    #pragma unroll
    for (int d = 0; d < 64; ++d) acc += mL[d] * wp[d * 768];
    T[((b * 12 + hh) * 12 + c) * 768 + e] = acc;
}

// ---- K3: per (b,n): h[e] = bo[e] + sum_c T[b][hc(n,c)][c][e]; +hs; LayerNorm. ----
__global__ __launch_bounds__(256) void out_kernel(
    const float* __restrict__ T, const float* __restrict__ hs,
    const float* __restrict__ bo, const float* __restrict__ ln_g,
    const float* __restrict__ ln_b, float* __restrict__ out)
{
    int b = blockIdx.x, n = blockIdx.y;
    int t = threadIdx.x;
    __shared__ float red[256];

    float x[3];
    float xs = 0.f;
    #pragma unroll
    for (int r = 0; r < 3; ++r) {
        int e = t + r * 256;
        float h = bo[e];
        #pragma unroll
        for (int c = 0; c < 12; ++c) {
            int hc = (12 * n + c) >> 8;
            h += T[((b * 12 + hc) * 12 + c) * 768 + e];
        }
        x[r] = h + hs[(b * 256 + n) * 768 + e];
        xs += x[r];
    }

    red[t] = xs;
    __syncthreads();
    for (int s = 128; s > 0; s >>= 1) {
        if (t < s) red[t] += red[t + s];
        __syncthreads();
    }
    float mu = red[0] * (1.0f / 768.0f);
    __syncthreads();

    float vs = 0.f;
    #pragma unroll
    for (int r = 0; r < 3; ++r) { float c = x[r] - mu; vs += c * c; }
    red[t] = vs;
    __syncthreads();
    for (int s = 128; s > 0; s >>= 1) {
        if (t < s) red[t] += red[t + s];
        __syncthreads();
    }
    float rstd = rsqrtf(red[0] * (1.0f / 768.0f) + 1e-12f);

    #pragma unroll
    for (int r = 0; r < 3; ++r) {
        int e = t + r * 256;
        float y = (x[r] - mu) * rstd * ln_g[e] + ln_b[e];
        out[(b * 256 + n) * 768 + e] = y;
    }
}

extern "C" void kernel_launch(void* const* d_in, const int* in_sizes, int n_in,
                              void* d_out, int out_size, void* d_ws, size_t ws_size,
                              hipStream_t stream) {
    const float* hs   = (const float*)d_in[0];
    // d_in[1..5] (mask, Wq, bq, Wk, bk): numerically dead (see header)
    const float* Wv   = (const float*)d_in[6];
    const float* bv   = (const float*)d_in[7];
    const float* Wo   = (const float*)d_in[8];
    const float* bo   = (const float*)d_in[9];
    const float* ln_g = (const float*)d_in[10];
    const float* ln_b = (const float*)d_in[11];

    char* ws = (char*)d_ws;
    float* Mpart = (float*)(ws + 196608);
    float* T     = (float*)(ws + 294912);

    msum_kernel<<<dim3(2, 3, 12),  256, 0, stream>>>(hs, Wv, Mpart);
    tmat_kernel<<<dim3(2, 12, 12), 768, 0, stream>>>(Mpart, bv, Wo, T);
    out_kernel <<<dim3(2, 256),    256, 0, stream>>>(T, hs, bo, ln_g, ln_b,
                                                     (float*)d_out);
}

// Round 4
// 93.274 us; speedup vs baseline: 2.7435x; 1.0212x over previous
//
#include <hip/hip_runtime.h>

// B=2, N=256, E=768, H=12, D=64. Inputs fp32, output fp32.
//
// Exact-math shortcut (validated in prior session):
//   attn scores (1+g/10)^-64.5 <= ~4e-9 uniformly => softmax uniform to 4e-9
//   => attn_out[b,h,i,:] = mean_j V[b,h,j,:] (independent of i)
//   => out = LN(hs + reshape_raw(tiled col-means of V) @ Wo + bo)
//
// Raw reshape [B,H,N,D]->[B,N,E]: row (b,n) chunk c comes from head hc=(12n+c)>>8:
//   h[b,n,e] = sum_c T[b][hc][c][e],
//   T[b][hh][c][e] = sum_d M[b][hh*64+d] * Wo[c*64+d][e],
//   M[b][:] = (sum_n hs[b,n,:]) @ Wv / 256 + bv.
//
// R10: micro-opts on the two cheapest-to-improve kernels (3-kernel structure
// is forced: each link is a grid-wide dep; cg::grid.sync measured ~50us/sync
// in R7, spin-barrier not better than ~1.5us graph gaps).
//  - tmat: 3 hh per Wo-panel read (grid (2,4,12)) -> Wo L2 traffic 56->19MB;
//    per-(hh,c,e) d-order unchanged => bit-identical T.
//  - out: 192 thr x float4 (16B/lane), wave-shuffle LN reductions (2 barriers
//    instead of 16). Per-e accumulation order unchanged; reduce order fp-noise.
//  - msum: unchanged (proven R9).
//
// ws layout (bytes):
//   Mpart f32[2][12][768]     @ 196608   ( 73728)  i-chunk partial M
//   T     f32[2][12][12][768] @ 294912   (884736)

// ---- K1: fused colsum+meanv. grid (2,3,12), block 256: (b, e-range, i-chunk). ----
__global__ __launch_bounds__(256) void msum_kernel(
    const float* __restrict__ hs, const float* __restrict__ Wv,
    float* __restrict__ Mpart)
{
    const int b = blockIdx.x, eg = blockIdx.y, ic = blockIdx.z;
    const int t = threadIdx.x;
    __shared__ float pL[16][64];   // 16-row-group partial colsums, our 64 cols
    __shared__ float hsumL[64];

    // Stage A: thread (rgrp, j4) sums 16 consecutive rows of one float4 column
    // group. Per 16-lane group: 256B contiguous loads.
    {
        const int j4 = t & 15;          // float4 chunk within 64 cols
        const int rgrp = t >> 4;        // 16-row group
        const float* pb = hs + b * 196608 + (rgrp * 16) * 768 + ic * 64 + j4 * 4;
        float4 s = make_float4(0.f, 0.f, 0.f, 0.f);
        #pragma unroll
        for (int r = 0; r < 16; ++r) {
            const float4 v = *(const float4*)(pb + r * 768);
            s.x += v.x; s.y += v.y; s.z += v.z; s.w += v.w;
        }
        *(float4*)&pL[rgrp][j4 * 4] = s;
    }
    __syncthreads();

    // Stage B: reduce 16 row-group partials per column (2-way LDS alias, free).
    if (t < 64) {
        float s = 0.f;
        #pragma unroll
        for (int g = 0; g < 16; ++g) s += pL[g][t];
        hsumL[t] = s;
    }
    __syncthreads();

    // Stage C: partial M for this i-chunk over our 256-e range (coalesced).
    const int e = eg * 256 + t;
    float acc = 0.f;
    #pragma unroll 8
    for (int ii = 0; ii < 64; ++ii)
        acc += hsumL[ii] * Wv[(ic * 64 + ii) * 768 + e];
    Mpart[(b * 12 + ic) * 768 + e] = acc;
}

// ---- K2: T[b][hh][c][e] = sum_d M[b][hh*64+d] * Wo[c*64+d][e].
//      grid (2,4,12) = (b, hh-group-of-3, c), block 768. 3 hh per Wo panel. ----
__global__ __launch_bounds__(768) void tmat_kernel(
    const float* __restrict__ Mpart, const float* __restrict__ bv,
    const float* __restrict__ Wo, float* __restrict__ T)
{
    const int b = blockIdx.x, hg = blockIdx.y, c = blockIdx.z;
    const int e = threadIdx.x;
    __shared__ float mL[3][64];

    if (e < 192) {
        const int k = e >> 6, d = e & 63;
        const int col = (hg * 3 + k) * 64 + d;
        float m = 0.f;
        #pragma unroll
        for (int ic = 0; ic < 12; ++ic) m += Mpart[(b * 12 + ic) * 768 + col];
        mL[k][d] = m * (1.0f / 256.0f) + bv[col];
    }
    __syncthreads();

    const float* wp = Wo + (c * 64) * 768 + e;
    float acc0 = 0.f, acc1 = 0.f, acc2 = 0.f;
    #pragma unroll
    for (int d = 0; d < 64; ++d) {
        const float wv = wp[d * 768];
        acc0 += mL[0][d] * wv;
        acc1 += mL[1][d] * wv;
        acc2 += mL[2][d] * wv;
    }
    const int hh0 = hg * 3;
    T[((b * 12 + hh0 + 0) * 12 + c) * 768 + e] = acc0;
    T[((b * 12 + hh0 + 1) * 12 + c) * 768 + e] = acc1;
    T[((b * 12 + hh0 + 2) * 12 + c) * 768 + e] = acc2;
}

// ---- K3: per (b,n): h[e] = bo[e] + sum_c T[b][hc(n,c)][c][e]; +hs; LayerNorm.
//      grid (2,256), block 192; each thread owns 4 consecutive e (float4). ----
__global__ __launch_bounds__(192) void out_kernel(
    const float* __restrict__ T, const float* __restrict__ hs,
    const float* __restrict__ bo, const float* __restrict__ ln_g,
    const float* __restrict__ ln_b, float* __restrict__ out)
{
    const int b = blockIdx.x, n = blockIdx.y;
    const int t = threadIdx.x;
    const int wave = t >> 6, lane = t & 63;
    const int e0 = t * 4;
    __shared__ float sm1[3];
    __shared__ float sm2[3];

    float4 x = *(const float4*)(bo + e0);
    #pragma unroll
    for (int c = 0; c < 12; ++c) {
        const int hc = (12 * n + c) >> 8;
        const float4 tv = *(const float4*)(T + ((b * 12 + hc) * 12 + c) * 768 + e0);
        x.x += tv.x; x.y += tv.y; x.z += tv.z; x.w += tv.w;
    }
    {
        const float4 hv = *(const float4*)(hs + (b * 256 + n) * 768 + e0);
        x.x += hv.x; x.y += hv.y; x.z += hv.z; x.w += hv.w;
    }

    // mean
    float wr = x.x + x.y + x.z + x.w;
    #pragma unroll
    for (int off = 32; off > 0; off >>= 1) wr += __shfl_down(wr, off, 64);
    if (lane == 0) sm1[wave] = wr;
    __syncthreads();
    const float mu = (sm1[0] + sm1[1] + sm1[2]) * (1.0f / 768.0f);

    // variance
    const float cx = x.x - mu, cy = x.y - mu, cz = x.z - mu, cw = x.w - mu;
    wr = cx * cx + cy * cy + cz * cz + cw * cw;
    #pragma unroll
    for (int off = 32; off > 0; off >>= 1) wr += __shfl_down(wr, off, 64);
    if (lane == 0) sm2[wave] = wr;
    __syncthreads();
    const float rstd = rsqrtf((sm2[0] + sm2[1] + sm2[2]) * (1.0f / 768.0f) + 1e-12f);

    const float4 g = *(const float4*)(ln_g + e0);
    const float4 bb = *(const float4*)(ln_b + e0);
    float4 y;
    y.x = cx * rstd * g.x + bb.x;
    y.y = cy * rstd * g.y + bb.y;
    y.z = cz * rstd * g.z + bb.z;
    y.w = cw * rstd * g.w + bb.w;
    *(float4*)(out + (b * 256 + n) * 768 + e0) = y;
}

extern "C" void kernel_launch(void* const* d_in, const int* in_sizes, int n_in,
                              void* d_out, int out_size, void* d_ws, size_t ws_size,
                              hipStream_t stream) {
    const float* hs   = (const float*)d_in[0];
    // d_in[1..5] (mask, Wq, bq, Wk, bk): numerically dead (see header)
    const float* Wv   = (const float*)d_in[6];
    const float* bv   = (const float*)d_in[7];
    const float* Wo   = (const float*)d_in[8];
    const float* bo   = (const float*)d_in[9];
    const float* ln_g = (const float*)d_in[10];
    const float* ln_b = (const float*)d_in[11];

    char* ws = (char*)d_ws;
    float* Mpart = (float*)(ws + 196608);
    float* T     = (float*)(ws + 294912);

    msum_kernel<<<dim3(2, 3, 12),  256, 0, stream>>>(hs, Wv, Mpart);
    tmat_kernel<<<dim3(2, 4, 12),  768, 0, stream>>>(Mpart, bv, Wo, T);
    out_kernel <<<dim3(2, 256),    192, 0, stream>>>(T, hs, bo, ln_g, ln_b,
                                                     (float*)d_out);
}